// Round 1
// baseline (1025.790 us; speedup 1.0000x reference)
//
#include <hip/hip_runtime.h>
#include <math.h>

// Problem constants
#define BQ 4        // query batches (B_TOTAL / WINDOW_SIZE)
#define CC 256      // channels
#define NN 512      // keypoints
#define HWD 65536   // H*W
#define WW 256      // W
#define MCHUNKS 16  // m-split across blocks
#define MLEN (HWD / MCHUNKS)  // 4096
#define TN 64       // n-tile per block
#define TM 256      // m-tile per inner iteration
#define CK 16       // c-chunk staged in LDS

// ws layout (floats)
#define WS_INVT 0                       // [4][65536]
#define WS_INVS (BQ * HWD)              // [4][512]
#define WS_PART (WS_INVS + BQ * NN)     // [4*512][MCHUNKS][4] (mx, s, su, sv)

// ---------------- tgt inverse norms: invt[b][m] = 1/max(||desc[2b+1,:,m]||, 1e-12)
__global__ void k_invt(const float* __restrict__ desc, float* __restrict__ ws) {
    int gid = blockIdx.x * blockDim.x + threadIdx.x;   // 0 .. 4*16384
    int b = gid >> 14;
    int m4 = (gid & 16383) << 2;
    const float* base = desc + (size_t)(2 * b + 1) * CC * HWD + m4;
    float ax = 0.f, ay = 0.f, az = 0.f, aw = 0.f;
    #pragma unroll 4
    for (int c = 0; c < CC; ++c) {
        float4 v = *reinterpret_cast<const float4*>(base + (size_t)c * HWD);
        ax = fmaf(v.x, v.x, ax); ay = fmaf(v.y, v.y, ay);
        az = fmaf(v.z, v.z, az); aw = fmaf(v.w, v.w, aw);
    }
    float4 r;
    r.x = 1.0f / fmaxf(sqrtf(ax), 1e-12f);
    r.y = 1.0f / fmaxf(sqrtf(ay), 1e-12f);
    r.z = 1.0f / fmaxf(sqrtf(az), 1e-12f);
    r.w = 1.0f / fmaxf(sqrtf(aw), 1e-12f);
    *reinterpret_cast<float4*>(ws + WS_INVT + b * HWD + m4) = r;
}

// ---------------- src inverse norms: invs[b][n]
__global__ void k_invs(const float* __restrict__ kdesc, float* __restrict__ ws) {
    int gid = blockIdx.x * blockDim.x + threadIdx.x;   // 0 .. 2048
    int b = gid >> 9;
    int n = gid & 511;
    const float* base = kdesc + (size_t)(2 * b) * CC * NN + n;
    float acc = 0.f;
    for (int c = 0; c < CC; ++c) {
        float v = base[(size_t)c * NN];
        acc = fmaf(v, v, acc);
    }
    ws[WS_INVS + b * NN + n] = 1.0f / fmaxf(sqrtf(acc), 1e-12f);
}

// ---------------- main: fp32 GEMM tile + fused online softmax with analytic V=(u,v,1)
__global__ __launch_bounds__(256) void k_main(
    const float* __restrict__ kdesc, const float* __restrict__ desc,
    const float* __restrict__ ws, float* __restrict__ part) {
    __shared__ float As[CK][TN];
    __shared__ float Bs[CK][TM];

    int chunk = blockIdx.x;   // m-chunk 0..15
    int ntile = blockIdx.y;   // 0..7
    int b = blockIdx.z;       // 0..3
    int tid = threadIdx.x;
    int tn = tid >> 5;        // 0..7  (8 row-groups)
    int tm = tid & 31;        // 0..31 (32 col-groups)
    int nbase = ntile * TN;

    const float* Ag = kdesc + (size_t)(2 * b) * CC * NN + nbase;
    const float* Bg = desc + (size_t)(2 * b + 1) * CC * HWD + (size_t)chunk * MLEN;
    const float* invt = ws + WS_INVT + (size_t)b * HWD + (size_t)chunk * MLEN;

    // per-row scale = invs * 1/temp
    float sA[8];
    #pragma unroll
    for (int r = 0; r < 8; ++r)
        sA[r] = ws[WS_INVS + b * NN + nbase + tn * 8 + r] * 100.0f;

    float mx[8], s[8], su[8], sv[8];
    #pragma unroll
    for (int r = 0; r < 8; ++r) { mx[r] = -1e30f; s[r] = 0.f; su[r] = 0.f; sv[r] = 0.f; }

    for (int mt = 0; mt < MLEN; mt += TM) {
        float acc[8][8];
        #pragma unroll
        for (int r = 0; r < 8; ++r)
            #pragma unroll
            for (int j = 0; j < 8; ++j) acc[r][j] = 0.f;

        for (int c0 = 0; c0 < CC; c0 += CK) {
            // issue global loads first (hide latency across the barrier)
            int ca = tid >> 4, na = (tid & 15) << 2;
            float4 va = *reinterpret_cast<const float4*>(Ag + (size_t)(c0 + ca) * NN + na);
            int cb = tid >> 6, mb = (tid & 63) << 2;
            float4 vb[4];
            #pragma unroll
            for (int i = 0; i < 4; ++i)
                vb[i] = *reinterpret_cast<const float4*>(Bg + (size_t)(c0 + cb + 4 * i) * HWD + mt + mb);

            __syncthreads();   // previous chunk fully consumed
            *reinterpret_cast<float4*>(&As[ca][na]) = va;
            #pragma unroll
            for (int i = 0; i < 4; ++i)
                *reinterpret_cast<float4*>(&Bs[cb + 4 * i][mb]) = vb[i];
            __syncthreads();

            #pragma unroll
            for (int c = 0; c < CK; ++c) {
                float a[8], bv[8];
                *reinterpret_cast<float4*>(&a[0]) = *reinterpret_cast<const float4*>(&As[c][tn * 8]);
                *reinterpret_cast<float4*>(&a[4]) = *reinterpret_cast<const float4*>(&As[c][tn * 8 + 4]);
                *reinterpret_cast<float4*>(&bv[0]) = *reinterpret_cast<const float4*>(&Bs[c][tm * 8]);
                *reinterpret_cast<float4*>(&bv[4]) = *reinterpret_cast<const float4*>(&Bs[c][tm * 8 + 4]);
                #pragma unroll
                for (int r = 0; r < 8; ++r)
                    #pragma unroll
                    for (int j = 0; j < 8; ++j)
                        acc[r][j] = fmaf(a[r], bv[j], acc[r][j]);
            }
        }

        // fused online softmax update for this 64n x 256m tile
        float it[8];
        *reinterpret_cast<float4*>(&it[0]) = *reinterpret_cast<const float4*>(invt + mt + tm * 8);
        *reinterpret_cast<float4*>(&it[4]) = *reinterpret_cast<const float4*>(invt + mt + tm * 8 + 4);
        int mg0 = chunk * MLEN + mt + tm * 8;          // global m of element j=0
        float vt = (float)(mg0 >> 8);                  // v constant over the tile row
        float ub = (float)(tm * 8);                    // u base for this thread

        #pragma unroll
        for (int r = 0; r < 8; ++r) {
            float L[8];
            #pragma unroll
            for (int j = 0; j < 8; ++j) L[j] = acc[r][j] * (sA[r] * it[j]);
            float tmax = L[0];
            #pragma unroll
            for (int j = 1; j < 8; ++j) tmax = fmaxf(tmax, L[j]);
            #pragma unroll
            for (int o = 1; o < 32; o <<= 1) tmax = fmaxf(tmax, __shfl_xor(tmax, o));
            float newm = fmaxf(mx[r], tmax);
            float ts = 0.f, tu = 0.f;
            #pragma unroll
            for (int j = 0; j < 8; ++j) {
                float p = __expf(L[j] - newm);
                ts += p;
                tu = fmaf(p, ub + (float)j, tu);
            }
            #pragma unroll
            for (int o = 1; o < 32; o <<= 1) {
                ts += __shfl_xor(ts, o);
                tu += __shfl_xor(tu, o);
            }
            float f = __expf(mx[r] - newm);
            s[r]  = fmaf(s[r], f, ts);
            su[r] = fmaf(su[r], f, tu);
            sv[r] = fmaf(sv[r], f, vt * ts);
            mx[r] = newm;
        }
    }

    if (tm == 0) {
        #pragma unroll
        for (int r = 0; r < 8; ++r) {
            int n = nbase + tn * 8 + r;
            float4 o4 = make_float4(mx[r], s[r], su[r], sv[r]);
            *reinterpret_cast<float4*>(part + ((size_t)(b * NN + n) * MCHUNKS + chunk) * 4) = o4;
        }
    }
}

// ---------------- finish: merge partials, coords, bilinear samples, weights
__global__ void k_finish(const float* __restrict__ kscores,
                         const float* __restrict__ kdesc,
                         const float* __restrict__ sdense,
                         const float* __restrict__ desc,
                         const float* __restrict__ ws,
                         float* __restrict__ out) {
    int bn = blockIdx.x;        // 0..2047
    int b = bn >> 9;
    int n = bn & 511;
    int tid = threadIdx.x;      // 256
    __shared__ float swf[8];
    __shared__ int sidx[4];
    __shared__ float red[4];

    if (tid == 0) {
        const float* p = ws + WS_PART + (size_t)bn * MCHUNKS * 4;
        float M = -1e30f;
        for (int k = 0; k < MCHUNKS; ++k) M = fmaxf(M, p[4 * k]);
        float S = 0.f, SU = 0.f, SV = 0.f;
        for (int k = 0; k < MCHUNKS; ++k) {
            float f = __expf(p[4 * k] - M);
            S  = fmaf(p[4 * k + 1], f, S);
            SU = fmaf(p[4 * k + 2], f, SU);
            SV = fmaf(p[4 * k + 3], f, SV);
        }
        float u = SU / S, v = SV / S;
        out[bn * 2 + 0] = u;
        out[bn * 2 + 1] = v;

        float uc = fminf(fmaxf(u, 0.f), 255.f);
        float vc = fminf(fmaxf(v, 0.f), 255.f);
        float u0 = floorf(uc), v0 = floorf(vc);
        float u1 = fminf(u0 + 1.f, 255.f), v1 = fminf(v0 + 1.f, 255.f);
        float wu = uc - u0, wv = vc - v0;
        int i00 = (int)v0 * WW + (int)u0;
        int i01 = (int)v0 * WW + (int)u1;
        int i10 = (int)v1 * WW + (int)u0;
        int i11 = (int)v1 * WW + (int)u1;
        float w00 = (1.f - wv) * (1.f - wu), w01 = (1.f - wv) * wu;
        float w10 = wv * (1.f - wu),         w11 = wv * wu;

        const float* sd = sdense + (size_t)(2 * b + 1) * HWD;
        float ps = w00 * sd[i00] + w01 * sd[i01] + w10 * sd[i10] + w11 * sd[i11];

        const float* it = ws + WS_INVT + (size_t)b * HWD;
        swf[0] = w00 * it[i00]; swf[1] = w01 * it[i01];
        swf[2] = w10 * it[i10]; swf[3] = w11 * it[i11];
        swf[4] = ps;
        sidx[0] = i00; sidx[1] = i01; sidx[2] = i10; sidx[3] = i11;
    }
    __syncthreads();

    int c = tid;
    const float* dcol = desc + (size_t)(2 * b + 1) * CC * HWD + (size_t)c * HWD;
    float pd = swf[0] * dcol[sidx[0]] + swf[1] * dcol[sidx[1]]
             + swf[2] * dcol[sidx[2]] + swf[3] * dcol[sidx[3]];
    float sc = kdesc[(size_t)(2 * b) * CC * NN + (size_t)c * NN + n];
    float t = pd * sc;
    #pragma unroll
    for (int o = 32; o > 0; o >>= 1) t += __shfl_xor(t, o);
    if ((tid & 63) == 0) red[tid >> 6] = t;
    __syncthreads();
    if (tid == 0) {
        float dot = red[0] + red[1] + red[2] + red[3];
        float invs = ws[WS_INVS + b * NN + n];
        float dms = dot * invs * (1.0f / 256.0f);
        float w = 0.5f * (dms + 1.0f) * kscores[(size_t)(2 * b) * NN + n] * swf[4];
        out[BQ * NN * 2 + bn] = w;
    }
}

extern "C" void kernel_launch(void* const* d_in, const int* in_sizes, int n_in,
                              void* d_out, int out_size, void* d_ws, size_t ws_size,
                              hipStream_t stream) {
    const float* kscores = (const float*)d_in[0];  // (8,1,512)
    const float* kdesc   = (const float*)d_in[1];  // (8,256,512)
    const float* sdense  = (const float*)d_in[2];  // (8,1,256,256)
    const float* desc    = (const float*)d_in[3];  // (8,256,256,256)
    float* out = (float*)d_out;                    // 4096 coords + 2048 weights
    float* ws  = (float*)d_ws;

    hipLaunchKernelGGL(k_invt, dim3(BQ * HWD / 4 / 256), dim3(256), 0, stream, desc, ws);
    hipLaunchKernelGGL(k_invs, dim3(BQ * NN / 256), dim3(256), 0, stream, kdesc, ws);
    hipLaunchKernelGGL(k_main, dim3(MCHUNKS, NN / TN, BQ), dim3(256), 0, stream,
                       kdesc, desc, ws, ws + WS_PART);
    hipLaunchKernelGGL(k_finish, dim3(BQ * NN), dim3(256), 0, stream,
                       kscores, kdesc, sdense, desc, ws, out);
}

// Round 3
// 351.558 us; speedup vs baseline: 2.9178x; 2.9178x over previous
//
#include <hip/hip_runtime.h>
#include <math.h>

#define BQ 4
#define CC 256
#define NN 512
#define HWD 65536
#define WW 256

typedef __attribute__((ext_vector_type(8))) short bf16x8;
typedef __attribute__((ext_vector_type(4))) float f32x4;

// ---------------- fast-path ws byte offsets ----------------
#define OB_INVT 0u
#define OB_INVS 1048576u
#define OB_PART 1056768u          // [4*512][16][3] f32
#define OB_AHI  2097152u          // [4][8][512][32] bf16
#define OB_ALO  3145728u
#define OB_BHI  4194304u          // [4][8][65536][32] bf16
#define OB_BLO  138412032u
#define WS_REQ  272629760ull

__device__ inline unsigned short f2bf(float x) {
    unsigned u = __float_as_uint(x);
    u += 0x7fffu + ((u >> 16) & 1u);
    return (unsigned short)(u >> 16);
}
__device__ inline float bf2f(unsigned short h) {
    return __uint_as_float(((unsigned)h) << 16);
}

#define GLDS16(g, l) __builtin_amdgcn_global_load_lds( \
    (const __attribute__((address_space(1))) void*)(g), \
    (__attribute__((address_space(3))) void*)(l), 16, 0, 0)

// ================= prep: normalize + bf16 hi/lo split + k-blocked pack =================
__global__ __launch_bounds__(256) void k_prep(
    const float* __restrict__ src, size_t batch_stride, int ld, int rows_tot,
    unsigned short* __restrict__ outHi, unsigned short* __restrict__ outLo,
    float* __restrict__ invout) {
    __shared__ float raw[CC * 64];
    __shared__ float sinv[64];
    int b = blockIdx.y;
    int mb = blockIdx.x * 64;
    int tid = threadIdx.x;
    const float* S = src + (size_t)b * batch_stride;
    #pragma unroll
    for (int it = 0; it < 16; ++it) {
        int c = it * 16 + (tid >> 4);
        int m4 = (tid & 15) * 4;
        float4 v = *reinterpret_cast<const float4*>(S + (size_t)c * ld + mb + m4);
        *reinterpret_cast<float4*>(&raw[c * 64 + (m4 ^ (c & 60))]) = v;
    }
    __syncthreads();
    {
        int m = tid >> 2, part = tid & 3;
        float acc = 0.f;
        for (int i = 0; i < 64; ++i) {
            int c = part * 64 + i;
            float x = raw[c * 64 + (m ^ (c & 60))];
            acc = fmaf(x, x, acc);
        }
        acc += __shfl_xor(acc, 1);
        acc += __shfl_xor(acc, 2);
        if (part == 0) {
            float iv = 1.0f / fmaxf(sqrtf(acc), 1e-12f);
            sinv[m] = iv;
            invout[(size_t)b * rows_tot + mb + m] = iv;
        }
    }
    __syncthreads();
    int m = tid & 63, sub = tid >> 6;
    float iv = sinv[m];
    for (int kc = 0; kc < 8; ++kc) {
        int c0 = kc * 32 + sub * 8;
        unsigned hh[4], ll[4];
        #pragma unroll
        for (int jp = 0; jp < 4; ++jp) {
            int c = c0 + jp * 2;
            int c1 = c + 1;
            float x0 = raw[c * 64 + (m ^ (c & 60))] * iv;
            float x1 = raw[c1 * 64 + (m ^ (c1 & 60))] * iv;
            unsigned short h0 = f2bf(x0), h1 = f2bf(x1);
            unsigned short l0 = f2bf(x0 - bf2f(h0)), l1 = f2bf(x1 - bf2f(h1));
            hh[jp] = (unsigned)h0 | ((unsigned)h1 << 16);
            ll[jp] = (unsigned)l0 | ((unsigned)l1 << 16);
        }
        size_t base = ((size_t)(b * 8 + kc) * rows_tot + mb + m) * 32 + sub * 8;
        *reinterpret_cast<uint4*>(outHi + base) = make_uint4(hh[0], hh[1], hh[2], hh[3]);
        *reinterpret_cast<uint4*>(outLo + base) = make_uint4(ll[0], ll[1], ll[2], ll[3]);
    }
}

// ================= main: 3-pass bf16 MFMA GEMM + fused fixed-max softmax =================
// Grid 256 blocks: block = (b, chunk, ntile). Tile 128n x 256m/step, m-chunk 4096.
// LDS double buffer: per buf 48KB = A_hi 8K | A_lo 8K | B_hi 16K | B_lo 16K.
__global__ __launch_bounds__(512, 2) void k_main2(
    const unsigned short* __restrict__ Ah, const unsigned short* __restrict__ Al,
    const unsigned short* __restrict__ Bh, const unsigned short* __restrict__ Bl,
    float* __restrict__ part) {
    __shared__ __align__(16) char smem[98304];

    int p = blockIdx.x;
    int xcd = p & 7, slot = p >> 3;
    int g = slot >> 2, nt = slot & 3;
    int pair = xcd * 8 + g;
    int bb = pair >> 4, chunk = pair & 15;
    int nbase = nt * 128;

    int tid = threadIdx.x;
    int w = tid >> 6, lane = tid & 63;
    int wn = w >> 2, wm = w & 3;
    int lrow = lane & 15, lkh = lane >> 4;
    int key = (lrow >> 1) & 3;

    // staging source offsets (elem units) for linear-dest + pre-swizzled source
    int sA = tid * 16;
    int rA = sA >> 6, slA = (sA >> 4) & 3;
    int seA = (rA << 5) + ((slA ^ ((rA >> 1) & 3)) << 3);
    int sB1 = 8192 + tid * 16;
    int rB1 = sB1 >> 6, slB1 = (sB1 >> 4) & 3;
    int seB1 = (rB1 << 5) + ((slB1 ^ ((rB1 >> 1) & 3)) << 3);
    int wb = w * 1024;   // wave-uniform LDS dest base within region

    // frag ds_read offsets (shorts): swizzled
    int aoff = ((wn * 64 + lrow) << 5) + ((lkh ^ key) << 3);
    int boff = ((wm * 64 + lrow) << 5) + ((lkh ^ key) << 3);

    float s_[4][4], su_[4][4], sv_[4][4];
    #pragma unroll
    for (int i = 0; i < 4; ++i)
        #pragma unroll
        for (int j = 0; j < 4; ++j) { s_[i][j] = 0.f; su_[i][j] = 0.f; sv_[i][j] = 0.f; }

    #define STAGE(bs, ms, kc) do {                                              \
        char* L = smem + (bs) * 49152;                                          \
        size_t aB = ((size_t)(bb * 8 + (kc)) * 512 + nbase) * 32;               \
        size_t bB = ((size_t)(bb * 8 + (kc)) * 65536 + chunk * 4096 + (ms) * 256) * 32; \
        GLDS16(Ah + aB + seA, L + wb);                                          \
        GLDS16(Al + aB + seA, L + 8192 + wb);                                   \
        GLDS16(Bh + bB + seA, L + 16384 + wb);                                  \
        GLDS16(Bh + bB + seB1, L + 16384 + 8192 + wb);                          \
        GLDS16(Bl + bB + seA, L + 32768 + wb);                                  \
        GLDS16(Bl + bB + seB1, L + 32768 + 8192 + wb);                          \
    } while (0)

    STAGE(0, 0, 0);
    asm volatile("s_waitcnt vmcnt(0)" ::: "memory");
    __syncthreads();

    int bs = 0;
    for (int ms = 0; ms < 16; ++ms) {
        f32x4 acc[4][4];
        #pragma unroll
        for (int i = 0; i < 4; ++i)
            #pragma unroll
            for (int j = 0; j < 4; ++j) acc[i][j] = (f32x4){0.f, 0.f, 0.f, 0.f};

        for (int kc = 0; kc < 8; ++kc) {
            int nkc = kc + 1;
            int nms = ms + (nkc >> 3);
            nkc &= 7;
            if (nms < 16) STAGE(bs ^ 1, nms, nkc);

            const short* base = (const short*)(smem + bs * 49152);
            bf16x8 ah[4], bh[4], x[4];
            #pragma unroll
            for (int rt = 0; rt < 4; ++rt)
                ah[rt] = *reinterpret_cast<const bf16x8*>(base + aoff + rt * 512);
            #pragma unroll
            for (int ct = 0; ct < 4; ++ct)
                bh[ct] = *reinterpret_cast<const bf16x8*>(base + 8192 + boff + ct * 512);
            #pragma unroll
            for (int rt = 0; rt < 4; ++rt)
                #pragma unroll
                for (int ct = 0; ct < 4; ++ct)
                    acc[rt][ct] = __builtin_amdgcn_mfma_f32_16x16x32_bf16(ah[rt], bh[ct], acc[rt][ct], 0, 0, 0);
            #pragma unroll
            for (int ct = 0; ct < 4; ++ct)
                x[ct] = *reinterpret_cast<const bf16x8*>(base + 16384 + boff + ct * 512);  // B_lo
            #pragma unroll
            for (int rt = 0; rt < 4; ++rt)
                #pragma unroll
                for (int ct = 0; ct < 4; ++ct)
                    acc[rt][ct] = __builtin_amdgcn_mfma_f32_16x16x32_bf16(ah[rt], x[ct], acc[rt][ct], 0, 0, 0);
            #pragma unroll
            for (int rt = 0; rt < 4; ++rt)
                x[rt] = *reinterpret_cast<const bf16x8*>(base + 4096 + aoff + rt * 512);   // A_lo
            #pragma unroll
            for (int rt = 0; rt < 4; ++rt)
                #pragma unroll
                for (int ct = 0; ct < 4; ++ct)
                    acc[rt][ct] = __builtin_amdgcn_mfma_f32_16x16x32_bf16(x[rt], bh[ct], acc[rt][ct], 0, 0, 0);

            asm volatile("s_waitcnt vmcnt(0)" ::: "memory");
            __syncthreads();
            bs ^= 1;
        }

        // fused softmax accumulation: p = exp(100*(dot-1)), fixed max (cos <= 1)
        float vstep = (float)(chunk * 16 + ms);
        #pragma unroll
        for (int rt = 0; rt < 4; ++rt) {
            #pragma unroll
            for (int reg = 0; reg < 4; ++reg) {
                float ts = 0.f, tu = 0.f;
                #pragma unroll
                for (int ct = 0; ct < 4; ++ct) {
                    float L = acc[rt][ct][reg];
                    float pz = __expf(fmaf(L, 100.f, -100.f));
                    ts += pz;
                    tu = fmaf(pz, (float)(wm * 64 + ct * 16 + lrow), tu);
                }
                s_[rt][reg] += ts;
                su_[rt][reg] += tu;
                sv_[rt][reg] = fmaf(vstep, ts, sv_[rt][reg]);
            }
        }
    }

    // ---- cross-lane (16 lrow) reduce, then cross-wm reduce through LDS ----
    // After the final in-loop barrier no wave touches smem again -> reuse it.
    float* lred = (float*)smem;   // [8 waves][64 n_local][3]
    #pragma unroll
    for (int rt = 0; rt < 4; ++rt) {
        #pragma unroll
        for (int reg = 0; reg < 4; ++reg) {
            float a = s_[rt][reg], b2 = su_[rt][reg], c2 = sv_[rt][reg];
            #pragma unroll
            for (int o = 1; o < 16; o <<= 1) {
                a += __shfl_xor(a, o);
                b2 += __shfl_xor(b2, o);
                c2 += __shfl_xor(c2, o);
            }
            if (lrow == 0) {
                int nl = rt * 16 + lkh * 4 + reg;
                lred[(w * 64 + nl) * 3 + 0] = a;
                lred[(w * 64 + nl) * 3 + 1] = b2;
                lred[(w * 64 + nl) * 3 + 2] = c2;
            }
        }
    }
    __syncthreads();
    if (tid < 128) {
        int wnl = tid >> 6, nl = tid & 63;
        float a = 0.f, b2 = 0.f, c2 = 0.f;
        #pragma unroll
        for (int q = 0; q < 4; ++q) {
            const float* p2 = &lred[((wnl * 4 + q) * 64 + nl) * 3];
            a += p2[0]; b2 += p2[1]; c2 += p2[2];
        }
        int n = nbase + wnl * 64 + nl;
        float* dst = part + ((size_t)(bb * 512 + n) * 16 + chunk) * 3;
        dst[0] = a; dst[1] = b2; dst[2] = c2;
    }
    #undef STAGE
}

// ================= finish =================
__global__ void k_finish2(const float* __restrict__ kscores,
                          const float* __restrict__ kdesc,
                          const float* __restrict__ sdense,
                          const float* __restrict__ desc,
                          const float* __restrict__ wsf,
                          float* __restrict__ out) {
    int bn = blockIdx.x;
    int b = bn >> 9, n = bn & 511;
    int tid = threadIdx.x;
    __shared__ float swf[8];
    __shared__ int sidx[4];
    __shared__ float red[4];

    if (tid == 0) {
        const float* pp = wsf + (OB_PART / 4) + (size_t)bn * 48;
        float S = 0.f, SU = 0.f, SV = 0.f;
        for (int k = 0; k < 16; ++k) {
            S += pp[k * 3]; SU += pp[k * 3 + 1]; SV += pp[k * 3 + 2];
        }
        float u = SU / S, v = SV / S;
        out[bn * 2 + 0] = u;
        out[bn * 2 + 1] = v;

        float uc = fminf(fmaxf(u, 0.f), 255.f);
        float vc = fminf(fmaxf(v, 0.f), 255.f);
        float u0 = floorf(uc), v0 = floorf(vc);
        float u1 = fminf(u0 + 1.f, 255.f), v1 = fminf(v0 + 1.f, 255.f);
        float wu = uc - u0, wv = vc - v0;
        int i00 = (int)v0 * WW + (int)u0;
        int i01 = (int)v0 * WW + (int)u1;
        int i10 = (int)v1 * WW + (int)u0;
        int i11 = (int)v1 * WW + (int)u1;
        float w00 = (1.f - wv) * (1.f - wu), w01 = (1.f - wv) * wu;
        float w10 = wv * (1.f - wu),         w11 = wv * wu;

        const float* sd = sdense + (size_t)(2 * b + 1) * HWD;
        float ps = w00 * sd[i00] + w01 * sd[i01] + w10 * sd[i10] + w11 * sd[i11];

        const float* it = wsf + (size_t)b * HWD;   // invt at offset 0
        swf[0] = w00 * it[i00]; swf[1] = w01 * it[i01];
        swf[2] = w10 * it[i10]; swf[3] = w11 * it[i11];
        swf[4] = ps;
        sidx[0] = i00; sidx[1] = i01; sidx[2] = i10; sidx[3] = i11;
    }
    __syncthreads();

    int c = tid;
    const float* dcol = desc + (size_t)(2 * b + 1) * CC * HWD + (size_t)c * HWD;
    float pd = swf[0] * dcol[sidx[0]] + swf[1] * dcol[sidx[1]]
             + swf[2] * dcol[sidx[2]] + swf[3] * dcol[sidx[3]];
    float sc = kdesc[(size_t)(2 * b) * CC * NN + (size_t)c * NN + n];
    float t = pd * sc;
    #pragma unroll
    for (int o = 32; o > 0; o >>= 1) t += __shfl_xor(t, o);
    if ((tid & 63) == 0) red[tid >> 6] = t;
    __syncthreads();
    if (tid == 0) {
        float dot = red[0] + red[1] + red[2] + red[3];
        float invs = wsf[OB_INVS / 4 + b * 512 + n];
        float dms = dot * invs * (1.0f / 256.0f);
        float wgt = 0.5f * (dms + 1.0f) * kscores[(size_t)(2 * b) * NN + n] * swf[4];
        out[BQ * NN * 2 + bn] = wgt;
    }
}

// ===================================================================================
// ======================= fallback path (round-1, small ws) =========================
// ===================================================================================
#define MCHUNKS 16
#define MLEN (HWD / MCHUNKS)
#define TN 64
#define TM 256
#define CK 16
#define WS_INVT 0
#define WS_INVS (BQ * HWD)
#define WS_PART (WS_INVS + BQ * NN)

__global__ void fb_invt(const float* __restrict__ desc, float* __restrict__ ws) {
    int gid = blockIdx.x * blockDim.x + threadIdx.x;
    int b = gid >> 14;
    int m4 = (gid & 16383) << 2;
    const float* base = desc + (size_t)(2 * b + 1) * CC * HWD + m4;
    float ax = 0.f, ay = 0.f, az = 0.f, aw = 0.f;
    #pragma unroll 4
    for (int c = 0; c < CC; ++c) {
        float4 v = *reinterpret_cast<const float4*>(base + (size_t)c * HWD);
        ax = fmaf(v.x, v.x, ax); ay = fmaf(v.y, v.y, ay);
        az = fmaf(v.z, v.z, az); aw = fmaf(v.w, v.w, aw);
    }
    float4 r;
    r.x = 1.0f / fmaxf(sqrtf(ax), 1e-12f);
    r.y = 1.0f / fmaxf(sqrtf(ay), 1e-12f);
    r.z = 1.0f / fmaxf(sqrtf(az), 1e-12f);
    r.w = 1.0f / fmaxf(sqrtf(aw), 1e-12f);
    *reinterpret_cast<float4*>(ws + WS_INVT + b * HWD + m4) = r;
}

__global__ void fb_invs(const float* __restrict__ kdesc, float* __restrict__ ws) {
    int gid = blockIdx.x * blockDim.x + threadIdx.x;
    int b = gid >> 9;
    int n = gid & 511;
    const float* base = kdesc + (size_t)(2 * b) * CC * NN + n;
    float acc = 0.f;
    for (int c = 0; c < CC; ++c) {
        float v = base[(size_t)c * NN];
        acc = fmaf(v, v, acc);
    }
    ws[WS_INVS + b * NN + n] = 1.0f / fmaxf(sqrtf(acc), 1e-12f);
}

__global__ __launch_bounds__(256) void fb_main(
    const float* __restrict__ kdesc, const float* __restrict__ desc,
    const float* __restrict__ ws, float* __restrict__ part) {
    __shared__ float As[CK][TN];
    __shared__ float Bs[CK][TM];
    int chunk = blockIdx.x, ntile = blockIdx.y, b = blockIdx.z;
    int tid = threadIdx.x;
    int tn = tid >> 5, tm = tid & 31;
    int nbase = ntile * TN;
    const float* Ag = kdesc + (size_t)(2 * b) * CC * NN + nbase;
    const float* Bg = desc + (size_t)(2 * b + 1) * CC * HWD + (size_t)chunk * MLEN;
    const float* invt = ws + WS_INVT + (size_t)b * HWD + (size_t)chunk * MLEN;
    float sA[8];
    #pragma unroll
    for (int r = 0; r < 8; ++r)
        sA[r] = ws[WS_INVS + b * NN + nbase + tn * 8 + r] * 100.0f;
    float mx[8], s[8], su[8], sv[8];
    #pragma unroll
    for (int r = 0; r < 8; ++r) { mx[r] = -1e30f; s[r] = 0.f; su[r] = 0.f; sv[r] = 0.f; }
    for (int mt = 0; mt < MLEN; mt += TM) {
        float acc[8][8];
        #pragma unroll
        for (int r = 0; r < 8; ++r)
            #pragma unroll
            for (int j = 0; j < 8; ++j) acc[r][j] = 0.f;
        for (int c0 = 0; c0 < CC; c0 += CK) {
            int ca = tid >> 4, na = (tid & 15) << 2;
            float4 va = *reinterpret_cast<const float4*>(Ag + (size_t)(c0 + ca) * NN + na);
            int cb = tid >> 6, mb = (tid & 63) << 2;
            float4 vb[4];
            #pragma unroll
            for (int i = 0; i < 4; ++i)
                vb[i] = *reinterpret_cast<const float4*>(Bg + (size_t)(c0 + cb + 4 * i) * HWD + mt + mb);
            __syncthreads();
            *reinterpret_cast<float4*>(&As[ca][na]) = va;
            #pragma unroll
            for (int i = 0; i < 4; ++i)
                *reinterpret_cast<float4*>(&Bs[cb + 4 * i][mb]) = vb[i];
            __syncthreads();
            #pragma unroll
            for (int cc = 0; cc < CK; ++cc) {
                float a[8], bv[8];
                *reinterpret_cast<float4*>(&a[0]) = *reinterpret_cast<const float4*>(&As[cc][tn * 8]);
                *reinterpret_cast<float4*>(&a[4]) = *reinterpret_cast<const float4*>(&As[cc][tn * 8 + 4]);
                *reinterpret_cast<float4*>(&bv[0]) = *reinterpret_cast<const float4*>(&Bs[cc][tm * 8]);
                *reinterpret_cast<float4*>(&bv[4]) = *reinterpret_cast<const float4*>(&Bs[cc][tm * 8 + 4]);
                #pragma unroll
                for (int r = 0; r < 8; ++r)
                    #pragma unroll
                    for (int j = 0; j < 8; ++j)
                        acc[r][j] = fmaf(a[r], bv[j], acc[r][j]);
            }
        }
        float it[8];
        *reinterpret_cast<float4*>(&it[0]) = *reinterpret_cast<const float4*>(invt + mt + tm * 8);
        *reinterpret_cast<float4*>(&it[4]) = *reinterpret_cast<const float4*>(invt + mt + tm * 8 + 4);
        int mg0 = chunk * MLEN + mt + tm * 8;
        float vt = (float)(mg0 >> 8);
        float ub = (float)(tm * 8);
        #pragma unroll
        for (int r = 0; r < 8; ++r) {
            float L[8];
            #pragma unroll
            for (int j = 0; j < 8; ++j) L[j] = acc[r][j] * (sA[r] * it[j]);
            float tmax = L[0];
            #pragma unroll
            for (int j = 1; j < 8; ++j) tmax = fmaxf(tmax, L[j]);
            #pragma unroll
            for (int o = 1; o < 32; o <<= 1) tmax = fmaxf(tmax, __shfl_xor(tmax, o));
            float newm = fmaxf(mx[r], tmax);
            float ts = 0.f, tu = 0.f;
            #pragma unroll
            for (int j = 0; j < 8; ++j) {
                float pz = __expf(L[j] - newm);
                ts += pz;
                tu = fmaf(pz, ub + (float)j, tu);
            }
            #pragma unroll
            for (int o = 1; o < 32; o <<= 1) {
                ts += __shfl_xor(ts, o);
                tu += __shfl_xor(tu, o);
            }
            float f = __expf(mx[r] - newm);
            s[r]  = fmaf(s[r], f, ts);
            su[r] = fmaf(su[r], f, tu);
            sv[r] = fmaf(sv[r], f, vt * ts);
            mx[r] = newm;
        }
    }
    if (tm == 0) {
        #pragma unroll
        for (int r = 0; r < 8; ++r) {
            int n = nbase + tn * 8 + r;
            float4 o4 = make_float4(mx[r], s[r], su[r], sv[r]);
            *reinterpret_cast<float4*>(part + ((size_t)(b * NN + n) * MCHUNKS + chunk) * 4) = o4;
        }
    }
}

__global__ void fb_finish(const float* __restrict__ kscores,
                          const float* __restrict__ kdesc,
                          const float* __restrict__ sdense,
                          const float* __restrict__ desc,
                          const float* __restrict__ ws,
                          float* __restrict__ out) {
    int bn = blockIdx.x;
    int b = bn >> 9, n = bn & 511;
    int tid = threadIdx.x;
    __shared__ float swf[8];
    __shared__ int sidx[4];
    __shared__ float red[4];
    if (tid == 0) {
        const float* pp = ws + WS_PART + (size_t)bn * MCHUNKS * 4;
        float M = -1e30f;
        for (int k = 0; k < MCHUNKS; ++k) M = fmaxf(M, pp[4 * k]);
        float S = 0.f, SU = 0.f, SV = 0.f;
        for (int k = 0; k < MCHUNKS; ++k) {
            float f = __expf(pp[4 * k] - M);
            S  = fmaf(pp[4 * k + 1], f, S);
            SU = fmaf(pp[4 * k + 2], f, SU);
            SV = fmaf(pp[4 * k + 3], f, SV);
        }
        float u = SU / S, v = SV / S;
        out[bn * 2 + 0] = u;
        out[bn * 2 + 1] = v;
        float uc = fminf(fmaxf(u, 0.f), 255.f);
        float vc = fminf(fmaxf(v, 0.f), 255.f);
        float u0 = floorf(uc), v0 = floorf(vc);
        float u1 = fminf(u0 + 1.f, 255.f), v1 = fminf(v0 + 1.f, 255.f);
        float wu = uc - u0, wv = vc - v0;
        int i00 = (int)v0 * WW + (int)u0;
        int i01 = (int)v0 * WW + (int)u1;
        int i10 = (int)v1 * WW + (int)u0;
        int i11 = (int)v1 * WW + (int)u1;
        float w00 = (1.f - wv) * (1.f - wu), w01 = (1.f - wv) * wu;
        float w10 = wv * (1.f - wu),         w11 = wv * wu;
        const float* sd = sdense + (size_t)(2 * b + 1) * HWD;
        float ps = w00 * sd[i00] + w01 * sd[i01] + w10 * sd[i10] + w11 * sd[i11];
        const float* it = ws + WS_INVT + (size_t)b * HWD;
        swf[0] = w00 * it[i00]; swf[1] = w01 * it[i01];
        swf[2] = w10 * it[i10]; swf[3] = w11 * it[i11];
        swf[4] = ps;
        sidx[0] = i00; sidx[1] = i01; sidx[2] = i10; sidx[3] = i11;
    }
    __syncthreads();
    int c = tid;
    const float* dcol = desc + (size_t)(2 * b + 1) * CC * HWD + (size_t)c * HWD;
    float pd = swf[0] * dcol[sidx[0]] + swf[1] * dcol[sidx[1]]
             + swf[2] * dcol[sidx[2]] + swf[3] * dcol[sidx[3]];
    float sc = kdesc[(size_t)(2 * b) * CC * NN + (size_t)c * NN + n];
    float t = pd * sc;
    #pragma unroll
    for (int o = 32; o > 0; o >>= 1) t += __shfl_xor(t, o);
    if ((tid & 63) == 0) red[tid >> 6] = t;
    __syncthreads();
    if (tid == 0) {
        float dot = red[0] + red[1] + red[2] + red[3];
        float invs = ws[WS_INVS + b * NN + n];
        float dms = dot * invs * (1.0f / 256.0f);
        float wgt = 0.5f * (dms + 1.0f) * kscores[(size_t)(2 * b) * NN + n] * swf[4];
        out[BQ * NN * 2 + bn] = wgt;
    }
}

// ===================================================================================
extern "C" void kernel_launch(void* const* d_in, const int* in_sizes, int n_in,
                              void* d_out, int out_size, void* d_ws, size_t ws_size,
                              hipStream_t stream) {
    const float* kscores = (const float*)d_in[0];  // (8,1,512)
    const float* kdesc   = (const float*)d_in[1];  // (8,256,512)
    const float* sdense  = (const float*)d_in[2];  // (8,1,256,256)
    const float* desc    = (const float*)d_in[3];  // (8,256,256,256)
    float* out = (float*)d_out;
    char* wsb = (char*)d_ws;
    float* wsf = (float*)d_ws;

    if (ws_size >= WS_REQ) {
        unsigned short* AHI = (unsigned short*)(wsb + OB_AHI);
        unsigned short* ALO = (unsigned short*)(wsb + OB_ALO);
        unsigned short* BHI = (unsigned short*)(wsb + OB_BHI);
        unsigned short* BLO = (unsigned short*)(wsb + OB_BLO);
        float* part = (float*)(wsb + OB_PART);

        // tgt (odd batches): normalize + split + pack; writes invt at ws[0]
        hipLaunchKernelGGL(k_prep, dim3(HWD / 64, BQ), dim3(256), 0, stream,
                           desc + (size_t)CC * HWD, (size_t)2 * CC * HWD, HWD, HWD,
                           BHI, BLO, wsf + (OB_INVT / 4));
        // src (even batches): writes invs
        hipLaunchKernelGGL(k_prep, dim3(NN / 64, BQ), dim3(256), 0, stream,
                           kdesc, (size_t)2 * CC * NN, NN, NN,
                           AHI, ALO, wsf + (OB_INVS / 4));
        hipLaunchKernelGGL(k_main2, dim3(256), dim3(512), 0, stream,
                           AHI, ALO, BHI, BLO, part);
        hipLaunchKernelGGL(k_finish2, dim3(BQ * NN), dim3(256), 0, stream,
                           kscores, kdesc, sdense, desc, wsf, out);
    } else {
        float* ws = wsf;
        hipLaunchKernelGGL(fb_invt, dim3(BQ * HWD / 4 / 256), dim3(256), 0, stream, desc, ws);
        hipLaunchKernelGGL(fb_invs, dim3(BQ * NN / 256), dim3(256), 0, stream, kdesc, ws);
        hipLaunchKernelGGL(fb_main, dim3(MCHUNKS, NN / TN, BQ), dim3(256), 0, stream,
                           kdesc, desc, ws, ws + WS_PART);
        hipLaunchKernelGGL(fb_finish, dim3(BQ * NN), dim3(256), 0, stream,
                           kscores, kdesc, sdense, desc, ws, out);
    }
}

// Round 4
// 314.603 us; speedup vs baseline: 3.2606x; 1.1175x over previous
//
#include <hip/hip_runtime.h>
#include <math.h>

#define BQ 4
#define CC 256
#define NN 512
#define HWD 65536
#define WW 256

typedef __attribute__((ext_vector_type(8))) short bf16x8;
typedef __attribute__((ext_vector_type(4))) float f32x4;

// ---------------- fast-path ws byte offsets ----------------
#define OB_INVT 0u
#define OB_INVS 1048576u
#define OB_PART 1056768u          // [4*512][16][3] f32
#define OB_AHI  2097152u          // [4][8][512][32] bf16
#define OB_ALO  3145728u
#define OB_BHI  4194304u          // [4][8][65536][32] bf16
#define OB_BLO  138412032u
#define WS_REQ  272629760ull

__device__ inline unsigned short f2bf(float x) {
    unsigned u = __float_as_uint(x);
    u += 0x7fffu + ((u >> 16) & 1u);
    return (unsigned short)(u >> 16);
}
__device__ inline float bf2f(unsigned short h) {
    return __uint_as_float(((unsigned)h) << 16);
}

#define GLDS16(g, l) __builtin_amdgcn_global_load_lds( \
    (const __attribute__((address_space(1))) void*)(g), \
    (__attribute__((address_space(3))) void*)(l), 16, 0, 0)

// ================= prep: normalize + bf16 hi/lo split + k-blocked pack =================
__global__ __launch_bounds__(256) void k_prep(
    const float* __restrict__ src, size_t batch_stride, int ld, int rows_tot,
    unsigned short* __restrict__ outHi, unsigned short* __restrict__ outLo,
    float* __restrict__ invout) {
    __shared__ float raw[CC * 64];
    __shared__ float sinv[64];
    int b = blockIdx.y;
    int mb = blockIdx.x * 64;
    int tid = threadIdx.x;
    const float* S = src + (size_t)b * batch_stride;
    #pragma unroll
    for (int it = 0; it < 16; ++it) {
        int c = it * 16 + (tid >> 4);
        int m4 = (tid & 15) * 4;
        float4 v = *reinterpret_cast<const float4*>(S + (size_t)c * ld + mb + m4);
        *reinterpret_cast<float4*>(&raw[c * 64 + (m4 ^ (c & 60))]) = v;
    }
    __syncthreads();
    {
        int m = tid >> 2, part = tid & 3;
        float acc = 0.f;
        for (int i = 0; i < 64; ++i) {
            int c = part * 64 + i;
            float x = raw[c * 64 + (m ^ (c & 60))];
            acc = fmaf(x, x, acc);
        }
        acc += __shfl_xor(acc, 1);
        acc += __shfl_xor(acc, 2);
        if (part == 0) {
            float iv = 1.0f / fmaxf(sqrtf(acc), 1e-12f);
            sinv[m] = iv;
            invout[(size_t)b * rows_tot + mb + m] = iv;
        }
    }
    __syncthreads();
    int m = tid & 63, sub = tid >> 6;
    float iv = sinv[m];
    for (int kc = 0; kc < 8; ++kc) {
        int c0 = kc * 32 + sub * 8;
        unsigned hh[4], ll[4];
        #pragma unroll
        for (int jp = 0; jp < 4; ++jp) {
            int c = c0 + jp * 2;
            int c1 = c + 1;
            float x0 = raw[c * 64 + (m ^ (c & 60))] * iv;
            float x1 = raw[c1 * 64 + (m ^ (c1 & 60))] * iv;
            unsigned short h0 = f2bf(x0), h1 = f2bf(x1);
            unsigned short l0 = f2bf(x0 - bf2f(h0)), l1 = f2bf(x1 - bf2f(h1));
            hh[jp] = (unsigned)h0 | ((unsigned)h1 << 16);
            ll[jp] = (unsigned)l0 | ((unsigned)l1 << 16);
        }
        size_t base = ((size_t)(b * 8 + kc) * rows_tot + mb + m) * 32 + sub * 8;
        *reinterpret_cast<uint4*>(outHi + base) = make_uint4(hh[0], hh[1], hh[2], hh[3]);
        *reinterpret_cast<uint4*>(outLo + base) = make_uint4(ll[0], ll[1], ll[2], ll[3]);
    }
}

// ================= main: 3-pass bf16 MFMA GEMM + fused fixed-max softmax =================
// Grid 256 blocks: block = (b, chunk, ntile). Tile 128n x 256m/step, m-chunk 4096.
// 3 LDS buffers x 48KB (counted-vmcnt pipeline, prefetch distance 2).
// Per buf: A_hi 8K | A_lo 8K | B_hi 16K | B_lo 16K.
__global__ __launch_bounds__(512, 2) void k_main2(
    const unsigned short* __restrict__ Ah, const unsigned short* __restrict__ Al,
    const unsigned short* __restrict__ Bh, const unsigned short* __restrict__ Bl,
    float* __restrict__ part) {
    __shared__ __align__(16) char smem[147456];

    int p = blockIdx.x;
    int xcd = p & 7, slot = p >> 3;
    int g = slot >> 2, nt = slot & 3;
    int pair = xcd * 8 + g;
    int bb = pair >> 4, chunk = pair & 15;
    int nbase = nt * 128;

    int tid = threadIdx.x;
    int w = tid >> 6, lane = tid & 63;
    int wn = w >> 2, wm = w & 3;
    int lrow = lane & 15, lkh = lane >> 4;
    int key = (lrow >> 1) & 3;

    // staging source offsets (elem units) for linear-dest + pre-swizzled source
    int sA = tid * 16;
    int rA = sA >> 6, slA = (sA >> 4) & 3;
    int seA = (rA << 5) + ((slA ^ ((rA >> 1) & 3)) << 3);
    int sB1 = 8192 + tid * 16;
    int rB1 = sB1 >> 6, slB1 = (sB1 >> 4) & 3;
    int seB1 = (rB1 << 5) + ((slB1 ^ ((rB1 >> 1) & 3)) << 3);
    int wb = w * 1024;   // wave-uniform LDS dest base within region

    // frag ds_read offsets (shorts): swizzled
    int aoff = ((wn * 64 + lrow) << 5) + ((lkh ^ key) << 3);
    int boff = ((wm * 64 + lrow) << 5) + ((lkh ^ key) << 3);

    float s_[4][4], su_[4][4], sv_[4][4];
    #pragma unroll
    for (int i = 0; i < 4; ++i)
        #pragma unroll
        for (int j = 0; j < 4; ++j) { s_[i][j] = 0.f; su_[i][j] = 0.f; sv_[i][j] = 0.f; }

    #define STAGE(bs, ms, kc) do {                                              \
        char* L = smem + (bs) * 49152;                                          \
        size_t aB = ((size_t)(bb * 8 + (kc)) * 512 + nbase) * 32;               \
        size_t bB = ((size_t)(bb * 8 + (kc)) * 65536 + chunk * 4096 + (ms) * 256) * 32; \
        GLDS16(Ah + aB + seA, L + wb);                                          \
        GLDS16(Al + aB + seA, L + 8192 + wb);                                   \
        GLDS16(Bh + bB + seA, L + 16384 + wb);                                  \
        GLDS16(Bh + bB + seB1, L + 16384 + 8192 + wb);                          \
        GLDS16(Bl + bB + seA, L + 32768 + wb);                                  \
        GLDS16(Bl + bB + seB1, L + 32768 + 8192 + wb);                          \
    } while (0)

    // prologue: prefetch phases 0 and 1
    STAGE(0, 0, 0);
    STAGE(1, 0, 1);

    int bufc = 0;   // buffer of current phase p = ms*8+kc; (p%3)
    for (int ms = 0; ms < 16; ++ms) {
        f32x4 acc[4][4];
        #pragma unroll
        for (int i = 0; i < 4; ++i)
            #pragma unroll
            for (int j = 0; j < 4; ++j) acc[i][j] = (f32x4){0.f, 0.f, 0.f, 0.f};

        #pragma unroll
        for (int kc = 0; kc < 8; ++kc) {
            // ---- wait: my STAGE(p) complete (6 newest loads may stay in flight) ----
            if (kc == 7 && ms == 15) {
                asm volatile("s_waitcnt vmcnt(0)" ::: "memory");
            } else {
                asm volatile("s_waitcnt vmcnt(6)" ::: "memory");
            }
            __builtin_amdgcn_s_barrier();
            __builtin_amdgcn_sched_barrier(0);

            // ---- prefetch phase p+2 into buf[(p+2)%3] ----
            int sb = bufc - 1; if (sb < 0) sb = 2;   // (bufc+2)%3
            if (kc < 6) {
                STAGE(sb, ms, kc + 2);
            } else if (ms < 15) {
                STAGE(sb, ms + 1, kc - 6);
            }

            const short* base = (const short*)(smem + bufc * 49152);
            bf16x8 ah[4], bh[4], x[4];
            #pragma unroll
            for (int rt = 0; rt < 4; ++rt)
                ah[rt] = *reinterpret_cast<const bf16x8*>(base + aoff + rt * 512);
            #pragma unroll
            for (int ct = 0; ct < 4; ++ct)
                bh[ct] = *reinterpret_cast<const bf16x8*>(base + 8192 + boff + ct * 512);
            __builtin_amdgcn_s_setprio(1);
            #pragma unroll
            for (int rt = 0; rt < 4; ++rt)
                #pragma unroll
                for (int ct = 0; ct < 4; ++ct)
                    acc[rt][ct] = __builtin_amdgcn_mfma_f32_16x16x32_bf16(ah[rt], bh[ct], acc[rt][ct], 0, 0, 0);
            #pragma unroll
            for (int ct = 0; ct < 4; ++ct)
                x[ct] = *reinterpret_cast<const bf16x8*>(base + 16384 + boff + ct * 512);  // B_lo
            #pragma unroll
            for (int rt = 0; rt < 4; ++rt)
                #pragma unroll
                for (int ct = 0; ct < 4; ++ct)
                    acc[rt][ct] = __builtin_amdgcn_mfma_f32_16x16x32_bf16(ah[rt], x[ct], acc[rt][ct], 0, 0, 0);
            #pragma unroll
            for (int rt = 0; rt < 4; ++rt)
                x[rt] = *reinterpret_cast<const bf16x8*>(base + 4096 + aoff + rt * 512);   // A_lo
            #pragma unroll
            for (int rt = 0; rt < 4; ++rt)
                #pragma unroll
                for (int ct = 0; ct < 4; ++ct)
                    acc[rt][ct] = __builtin_amdgcn_mfma_f32_16x16x32_bf16(x[rt], bh[ct], acc[rt][ct], 0, 0, 0);
            __builtin_amdgcn_s_setprio(0);

            bufc = bufc + 1; if (bufc > 2) bufc = 0;
        }

        // fused softmax accumulation: p = exp(100*(dot-1)), fixed max (cos <= 1)
        float vstep = (float)(chunk * 16 + ms);
        #pragma unroll
        for (int rt = 0; rt < 4; ++rt) {
            #pragma unroll
            for (int reg = 0; reg < 4; ++reg) {
                float ts = 0.f, tu = 0.f;
                #pragma unroll
                for (int ct = 0; ct < 4; ++ct) {
                    float L = acc[rt][ct][reg];
                    float pz = __expf(fmaf(L, 100.f, -100.f));
                    ts += pz;
                    tu = fmaf(pz, (float)(wm * 64 + ct * 16 + lrow), tu);
                }
                s_[rt][reg] += ts;
                su_[rt][reg] += tu;
                sv_[rt][reg] = fmaf(vstep, ts, sv_[rt][reg]);
            }
        }
    }

    // ---- cross-lane (16 lrow) reduce, then cross-wm reduce through LDS ----
    // All waves are past the last phase's barrier; buf0 region is dead -> reuse.
    float* lred = (float*)smem;   // [8 waves][64 n_local][3]
    #pragma unroll
    for (int rt = 0; rt < 4; ++rt) {
        #pragma unroll
        for (int reg = 0; reg < 4; ++reg) {
            float a = s_[rt][reg], b2 = su_[rt][reg], c2 = sv_[rt][reg];
            #pragma unroll
            for (int o = 1; o < 16; o <<= 1) {
                a += __shfl_xor(a, o);
                b2 += __shfl_xor(b2, o);
                c2 += __shfl_xor(c2, o);
            }
            if (lrow == 0) {
                int nl = rt * 16 + lkh * 4 + reg;
                lred[(w * 64 + nl) * 3 + 0] = a;
                lred[(w * 64 + nl) * 3 + 1] = b2;
                lred[(w * 64 + nl) * 3 + 2] = c2;
            }
        }
    }
    __syncthreads();
    if (tid < 128) {
        int wnl = tid >> 6, nl = tid & 63;
        float a = 0.f, b2 = 0.f, c2 = 0.f;
        #pragma unroll
        for (int q = 0; q < 4; ++q) {
            const float* p2 = &lred[((wnl * 4 + q) * 64 + nl) * 3];
            a += p2[0]; b2 += p2[1]; c2 += p2[2];
        }
        int n = nbase + wnl * 64 + nl;
        float* dst = part + ((size_t)(bb * 512 + n) * 16 + chunk) * 3;
        dst[0] = a; dst[1] = b2; dst[2] = c2;
    }
    #undef STAGE
}

// ================= finish =================
__global__ void k_finish2(const float* __restrict__ kscores,
                          const float* __restrict__ kdesc,
                          const float* __restrict__ sdense,
                          const float* __restrict__ desc,
                          const float* __restrict__ wsf,
                          float* __restrict__ out) {
    int bn = blockIdx.x;
    int b = bn >> 9, n = bn & 511;
    int tid = threadIdx.x;
    __shared__ float swf[8];
    __shared__ int sidx[4];
    __shared__ float red[4];

    if (tid == 0) {
        const float* pp = wsf + (OB_PART / 4) + (size_t)bn * 48;
        float S = 0.f, SU = 0.f, SV = 0.f;
        for (int k = 0; k < 16; ++k) {
            S += pp[k * 3]; SU += pp[k * 3 + 1]; SV += pp[k * 3 + 2];
        }
        float u = SU / S, v = SV / S;
        out[bn * 2 + 0] = u;
        out[bn * 2 + 1] = v;

        float uc = fminf(fmaxf(u, 0.f), 255.f);
        float vc = fminf(fmaxf(v, 0.f), 255.f);
        float u0 = floorf(uc), v0 = floorf(vc);
        float u1 = fminf(u0 + 1.f, 255.f), v1 = fminf(v0 + 1.f, 255.f);
        float wu = uc - u0, wv = vc - v0;
        int i00 = (int)v0 * WW + (int)u0;
        int i01 = (int)v0 * WW + (int)u1;
        int i10 = (int)v1 * WW + (int)u0;
        int i11 = (int)v1 * WW + (int)u1;
        float w00 = (1.f - wv) * (1.f - wu), w01 = (1.f - wv) * wu;
        float w10 = wv * (1.f - wu),         w11 = wv * wu;

        const float* sd = sdense + (size_t)(2 * b + 1) * HWD;
        float ps = w00 * sd[i00] + w01 * sd[i01] + w10 * sd[i10] + w11 * sd[i11];

        const float* it = wsf + (size_t)b * HWD;   // invt at offset 0
        swf[0] = w00 * it[i00]; swf[1] = w01 * it[i01];
        swf[2] = w10 * it[i10]; swf[3] = w11 * it[i11];
        swf[4] = ps;
        sidx[0] = i00; sidx[1] = i01; sidx[2] = i10; sidx[3] = i11;
    }
    __syncthreads();

    int c = tid;
    const float* dcol = desc + (size_t)(2 * b + 1) * CC * HWD + (size_t)c * HWD;
    float pd = swf[0] * dcol[sidx[0]] + swf[1] * dcol[sidx[1]]
             + swf[2] * dcol[sidx[2]] + swf[3] * dcol[sidx[3]];
    float sc = kdesc[(size_t)(2 * b) * CC * NN + (size_t)c * NN + n];
    float t = pd * sc;
    #pragma unroll
    for (int o = 32; o > 0; o >>= 1) t += __shfl_xor(t, o);
    if ((tid & 63) == 0) red[tid >> 6] = t;
    __syncthreads();
    if (tid == 0) {
        float dot = red[0] + red[1] + red[2] + red[3];
        float invs = wsf[OB_INVS / 4 + b * 512 + n];
        float dms = dot * invs * (1.0f / 256.0f);
        float wgt = 0.5f * (dms + 1.0f) * kscores[(size_t)(2 * b) * NN + n] * swf[4];
        out[BQ * NN * 2 + bn] = wgt;
    }
}

// ===================================================================================
// ======================= fallback path (round-1, small ws) =========================
// ===================================================================================
#define MCHUNKS 16
#define MLEN (HWD / MCHUNKS)
#define TN 64
#define TM 256
#define CK 16
#define WS_INVT 0
#define WS_INVS (BQ * HWD)
#define WS_PART (WS_INVS + BQ * NN)

__global__ void fb_invt(const float* __restrict__ desc, float* __restrict__ ws) {
    int gid = blockIdx.x * blockDim.x + threadIdx.x;
    int b = gid >> 14;
    int m4 = (gid & 16383) << 2;
    const float* base = desc + (size_t)(2 * b + 1) * CC * HWD + m4;
    float ax = 0.f, ay = 0.f, az = 0.f, aw = 0.f;
    #pragma unroll 4
    for (int c = 0; c < CC; ++c) {
        float4 v = *reinterpret_cast<const float4*>(base + (size_t)c * HWD);
        ax = fmaf(v.x, v.x, ax); ay = fmaf(v.y, v.y, ay);
        az = fmaf(v.z, v.z, az); aw = fmaf(v.w, v.w, aw);
    }
    float4 r;
    r.x = 1.0f / fmaxf(sqrtf(ax), 1e-12f);
    r.y = 1.0f / fmaxf(sqrtf(ay), 1e-12f);
    r.z = 1.0f / fmaxf(sqrtf(az), 1e-12f);
    r.w = 1.0f / fmaxf(sqrtf(aw), 1e-12f);
    *reinterpret_cast<float4*>(ws + WS_INVT + b * HWD + m4) = r;
}

__global__ void fb_invs(const float* __restrict__ kdesc, float* __restrict__ ws) {
    int gid = blockIdx.x * blockDim.x + threadIdx.x;
    int b = gid >> 9;
    int n = gid & 511;
    const float* base = kdesc + (size_t)(2 * b) * CC * NN + n;
    float acc = 0.f;
    for (int c = 0; c < CC; ++c) {
        float v = base[(size_t)c * NN];
        acc = fmaf(v, v, acc);
    }
    ws[WS_INVS + b * NN + n] = 1.0f / fmaxf(sqrtf(acc), 1e-12f);
}

__global__ __launch_bounds__(256) void fb_main(
    const float* __restrict__ kdesc, const float* __restrict__ desc,
    const float* __restrict__ ws, float* __restrict__ part) {
    __shared__ float As[CK][TN];
    __shared__ float Bs[CK][TM];
    int chunk = blockIdx.x, ntile = blockIdx.y, b = blockIdx.z;
    int tid = threadIdx.x;
    int tn = tid >> 5, tm = tid & 31;
    int nbase = ntile * TN;
    const float* Ag = kdesc + (size_t)(2 * b) * CC * NN + nbase;
    const float* Bg = desc + (size_t)(2 * b + 1) * CC * HWD + (size_t)chunk * MLEN;
    const float* invt = ws + WS_INVT + (size_t)b * HWD + (size_t)chunk * MLEN;
    float sA[8];
    #pragma unroll
    for (int r = 0; r < 8; ++r)
        sA[r] = ws[WS_INVS + b * NN + nbase + tn * 8 + r] * 100.0f;
    float mx[8], s[8], su[8], sv[8];
    #pragma unroll
    for (int r = 0; r < 8; ++r) { mx[r] = -1e30f; s[r] = 0.f; su[r] = 0.f; sv[r] = 0.f; }
    for (int mt = 0; mt < MLEN; mt += TM) {
        float acc[8][8];
        #pragma unroll
        for (int r = 0; r < 8; ++r)
            #pragma unroll
            for (int j = 0; j < 8; ++j) acc[r][j] = 0.f;
        for (int c0 = 0; c0 < CC; c0 += CK) {
            int ca = tid >> 4, na = (tid & 15) << 2;
            float4 va = *reinterpret_cast<const float4*>(Ag + (size_t)(c0 + ca) * NN + na);
            int cb = tid >> 6, mb = (tid & 63) << 2;
            float4 vb[4];
            #pragma unroll
            for (int i = 0; i < 4; ++i)
                vb[i] = *reinterpret_cast<const float4*>(Bg + (size_t)(c0 + cb + 4 * i) * HWD + mt + mb);
            __syncthreads();
            *reinterpret_cast<float4*>(&As[ca][na]) = va;
            #pragma unroll
            for (int i = 0; i < 4; ++i)
                *reinterpret_cast<float4*>(&Bs[cb + 4 * i][mb]) = vb[i];
            __syncthreads();
            #pragma unroll
            for (int cc = 0; cc < CK; ++cc) {
                float a[8], bv[8];
                *reinterpret_cast<float4*>(&a[0]) = *reinterpret_cast<const float4*>(&As[cc][tn * 8]);
                *reinterpret_cast<float4*>(&a[4]) = *reinterpret_cast<const float4*>(&As[cc][tn * 8 + 4]);
                *reinterpret_cast<float4*>(&bv[0]) = *reinterpret_cast<const float4*>(&Bs[cc][tm * 8]);
                *reinterpret_cast<float4*>(&bv[4]) = *reinterpret_cast<const float4*>(&Bs[cc][tm * 8 + 4]);
                #pragma unroll
                for (int r = 0; r < 8; ++r)
                    #pragma unroll
                    for (int j = 0; j < 8; ++j)
                        acc[r][j] = fmaf(a[r], bv[j], acc[r][j]);
            }
        }
        float it[8];
        *reinterpret_cast<float4*>(&it[0]) = *reinterpret_cast<const float4*>(invt + mt + tm * 8);
        *reinterpret_cast<float4*>(&it[4]) = *reinterpret_cast<const float4*>(invt + mt + tm * 8 + 4);
        int mg0 = chunk * MLEN + mt + tm * 8;
        float vt = (float)(mg0 >> 8);
        float ub = (float)(tm * 8);
        #pragma unroll
        for (int r = 0; r < 8; ++r) {
            float L[8];
            #pragma unroll
            for (int j = 0; j < 8; ++j) L[j] = acc[r][j] * (sA[r] * it[j]);
            float tmax = L[0];
            #pragma unroll
            for (int j = 1; j < 8; ++j) tmax = fmaxf(tmax, L[j]);
            #pragma unroll
            for (int o = 1; o < 32; o <<= 1) tmax = fmaxf(tmax, __shfl_xor(tmax, o));
            float newm = fmaxf(mx[r], tmax);
            float ts = 0.f, tu = 0.f;
            #pragma unroll
            for (int j = 0; j < 8; ++j) {
                float pz = __expf(L[j] - newm);
                ts += pz;
                tu = fmaf(pz, ub + (float)j, tu);
            }
            #pragma unroll
            for (int o = 1; o < 32; o <<= 1) {
                ts += __shfl_xor(ts, o);
                tu += __shfl_xor(tu, o);
            }
            float f = __expf(mx[r] - newm);
            s[r]  = fmaf(s[r], f, ts);
            su[r] = fmaf(su[r], f, tu);
            sv[r] = fmaf(sv[r], f, vt * ts);
            mx[r] = newm;
        }
    }
    if (tm == 0) {
        #pragma unroll
        for (int r = 0; r < 8; ++r) {
            int n = nbase + tn * 8 + r;
            float4 o4 = make_float4(mx[r], s[r], su[r], sv[r]);
            *reinterpret_cast<float4*>(part + ((size_t)(b * NN + n) * MCHUNKS + chunk) * 4) = o4;
        }
    }
}

__global__ void fb_finish(const float* __restrict__ kscores,
                          const float* __restrict__ kdesc,
                          const float* __restrict__ sdense,
                          const float* __restrict__ desc,
                          const float* __restrict__ ws,
                          float* __restrict__ out) {
    int bn = blockIdx.x;
    int b = bn >> 9, n = bn & 511;
    int tid = threadIdx.x;
    __shared__ float swf[8];
    __shared__ int sidx[4];
    __shared__ float red[4];
    if (tid == 0) {
        const float* pp = ws + WS_PART + (size_t)bn * MCHUNKS * 4;
        float M = -1e30f;
        for (int k = 0; k < MCHUNKS; ++k) M = fmaxf(M, pp[4 * k]);
        float S = 0.f, SU = 0.f, SV = 0.f;
        for (int k = 0; k < MCHUNKS; ++k) {
            float f = __expf(pp[4 * k] - M);
            S  = fmaf(pp[4 * k + 1], f, S);
            SU = fmaf(pp[4 * k + 2], f, SU);
            SV = fmaf(pp[4 * k + 3], f, SV);
        }
        float u = SU / S, v = SV / S;
        out[bn * 2 + 0] = u;
        out[bn * 2 + 1] = v;
        float uc = fminf(fmaxf(u, 0.f), 255.f);
        float vc = fminf(fmaxf(v, 0.f), 255.f);
        float u0 = floorf(uc), v0 = floorf(vc);
        float u1 = fminf(u0 + 1.f, 255.f), v1 = fminf(v0 + 1.f, 255.f);
        float wu = uc - u0, wv = vc - v0;
        int i00 = (int)v0 * WW + (int)u0;
        int i01 = (int)v0 * WW + (int)u1;
        int i10 = (int)v1 * WW + (int)u0;
        int i11 = (int)v1 * WW + (int)u1;
        float w00 = (1.f - wv) * (1.f - wu), w01 = (1.f - wv) * wu;
        float w10 = wv * (1.f - wu),         w11 = wv * wu;
        const float* sd = sdense + (size_t)(2 * b + 1) * HWD;
        float ps = w00 * sd[i00] + w01 * sd[i01] + w10 * sd[i10] + w11 * sd[i11];
        const float* it = ws + WS_INVT + (size_t)b * HWD;
        swf[0] = w00 * it[i00]; swf[1] = w01 * it[i01];
        swf[2] = w10 * it[i10]; swf[3] = w11 * it[i11];
        swf[4] = ps;
        sidx[0] = i00; sidx[1] = i01; sidx[2] = i10; sidx[3] = i11;
    }
    __syncthreads();
    int c = tid;
    const float* dcol = desc + (size_t)(2 * b + 1) * CC * HWD + (size_t)c * HWD;
    float pd = swf[0] * dcol[sidx[0]] + swf[1] * dcol[sidx[1]]
             + swf[2] * dcol[sidx[2]] + swf[3] * dcol[sidx[3]];
    float sc = kdesc[(size_t)(2 * b) * CC * NN + (size_t)c * NN + n];
    float t = pd * sc;
    #pragma unroll
    for (int o = 32; o > 0; o >>= 1) t += __shfl_xor(t, o);
    if ((tid & 63) == 0) red[tid >> 6] = t;
    __syncthreads();
    if (tid == 0) {
        float dot = red[0] + red[1] + red[2] + red[3];
        float invs = ws[WS_INVS + b * NN + n];
        float dms = dot * invs * (1.0f / 256.0f);
        float wgt = 0.5f * (dms + 1.0f) * kscores[(size_t)(2 * b) * NN + n] * swf[4];
        out[BQ * NN * 2 + bn] = wgt;
    }
}

// ===================================================================================
extern "C" void kernel_launch(void* const* d_in, const int* in_sizes, int n_in,
                              void* d_out, int out_size, void* d_ws, size_t ws_size,
                              hipStream_t stream) {
    const float* kscores = (const float*)d_in[0];  // (8,1,512)
    const float* kdesc   = (const float*)d_in[1];  // (8,256,512)
    const float* sdense  = (const float*)d_in[2];  // (8,1,256,256)
    const float* desc    = (const float*)d_in[3];  // (8,256,256,256)
    float* out = (float*)d_out;
    char* wsb = (char*)d_ws;
    float* wsf = (float*)d_ws;

    if (ws_size >= WS_REQ) {
        unsigned short* AHI = (unsigned short*)(wsb + OB_AHI);
        unsigned short* ALO = (unsigned short*)(wsb + OB_ALO);
        unsigned short* BHI = (unsigned short*)(wsb + OB_BHI);
        unsigned short* BLO = (unsigned short*)(wsb + OB_BLO);
        float* part = (float*)(wsb + OB_PART);

        // tgt (odd batches): normalize + split + pack; writes invt at ws[0]
        hipLaunchKernelGGL(k_prep, dim3(HWD / 64, BQ), dim3(256), 0, stream,
                           desc + (size_t)CC * HWD, (size_t)2 * CC * HWD, HWD, HWD,
                           BHI, BLO, wsf + (OB_INVT / 4));
        // src (even batches): writes invs
        hipLaunchKernelGGL(k_prep, dim3(NN / 64, BQ), dim3(256), 0, stream,
                           kdesc, (size_t)2 * CC * NN, NN, NN,
                           AHI, ALO, wsf + (OB_INVS / 4));
        hipLaunchKernelGGL(k_main2, dim3(256), dim3(512), 0, stream,
                           AHI, ALO, BHI, BLO, part);
        hipLaunchKernelGGL(k_finish2, dim3(BQ * NN), dim3(256), 0, stream,
                           kscores, kdesc, sdense, desc, wsf, out);
    } else {
        float* ws = wsf;
        hipLaunchKernelGGL(fb_invt, dim3(BQ * HWD / 4 / 256), dim3(256), 0, stream, desc, ws);
        hipLaunchKernelGGL(fb_invs, dim3(BQ * NN / 256), dim3(256), 0, stream, kdesc, ws);
        hipLaunchKernelGGL(fb_main, dim3(MCHUNKS, NN / TN, BQ), dim3(256), 0, stream,
                           kdesc, desc, ws, ws + WS_PART);
        hipLaunchKernelGGL(fb_finish, dim3(BQ * NN), dim3(256), 0, stream,
                           kscores, kdesc, sdense, desc, ws, out);
    }
}